// Round 9
// baseline (188.804 us; speedup 1.0000x reference)
//
#include <hip/hip_runtime.h>
#include <stdint.h>

#define B_ 128
#define N_ 512
#define I_ 256
#define M_ 32
#define D_ 16

typedef __attribute__((ext_vector_type(4))) float f32x4;
typedef __attribute__((ext_vector_type(4))) float float4v;
typedef __attribute__((ext_vector_type(8))) short short8;     // 8 bf16 MFMA frag
typedef __attribute__((ext_vector_type(4))) unsigned short ushort4v;

__device__ __forceinline__ float bf2f(unsigned short u) {
    union { unsigned int i; float f; } v; v.i = ((unsigned int)u) << 16; return v.f;
}
__device__ __forceinline__ unsigned short f2bf(float f) {
    union { float f; unsigned int i; } v; v.f = f;
    unsigned int r = v.i + 0x7FFFu + ((v.i >> 16) & 1u);   // RNE
    return (unsigned short)(r >> 16);
}

// volatile asm load: cannot be sunk/split by the scheduler (r8 lesson: the
// compiler serializes source-level prefetch regardless of VGPR budget).
#define GLOAD16(dst, ptr) \
    asm volatile("global_load_dwordx4 %0, %1, off" : "=&v"(dst) : "v"(ptr))

#define VMWAIT0() do { \
    asm volatile("s_waitcnt vmcnt(0)" ::: "memory"); \
    __builtin_amdgcn_sched_barrier(0); \
} while (0)

#define LGKM0_BARRIER() do { \
    asm volatile("s_waitcnt lgkmcnt(0)" ::: "memory"); \
    __builtin_amdgcn_sched_barrier(0); \
    __builtin_amdgcn_s_barrier(); \
    __builtin_amdgcn_sched_barrier(0); \
} while (0)

#define BARRIER() do { \
    __builtin_amdgcn_sched_barrier(0); \
    __builtin_amdgcn_s_barrier(); \
    __builtin_amdgcn_sched_barrier(0); \
} while (0)

// -----------------------------------------------------------------------------
// Kernel 1: inputs_hat[b,m,n,d] = sum_i x[b,n,i] * W[m,n,d,i]
// r7 tiling (128 b-rows x 64 cols per block, BK=64, 4096 blocks XCD-chunked).
// Staging via 12 volatile-asm global_load_dwordx4 per k-tile into pa/qa
// register double-buffer; own vmcnt/lgkmcnt management; raw s_barrier (loads
// for tile kt+1 stay in flight across tile kt's MFMA phase).
// -----------------------------------------------------------------------------
#define LDK 72   // 64 + 8 pad (ushort)

__global__ __launch_bounds__(256, 3) void hat_gemm(const float* __restrict__ x,
                                                   const float* __restrict__ W,
                                                   unsigned short* __restrict__ hat) {
    __shared__ unsigned short As[128][LDK];   // 18.4 KB
    __shared__ unsigned short Bs[64][LDK];    //  9.2 KB

    const int L   = blockIdx.x;
    const int xcd = L & 7;
    const int i   = L >> 3;
    const int n   = xcd * 64 + (i >> 3);
    const int mc  = i & 7;              // m in [mc*4, mc*4+4)

    const int tid  = threadIdx.x;
    const int lane = tid & 63;
    const int w    = tid >> 6;
    const int l15  = lane & 15;

    const int sgrp  = tid >> 4;         // 0..15
    const int klane = (tid & 15) * 4;

    const float* xrow = x + ((size_t)sgrp * N_ + n) * I_ + klane;
    const float* wrow = W + (((size_t)(mc * 4) * N_ + n) * D_ + sgrp) * I_ + klane;
    const size_t xstep = (size_t)16 * N_ * I_;
    const size_t wstep = (size_t)N_ * D_ * I_;

    float4v pa[8], pb[4], qa[8], qb[4];

    f32x4 acc[2][4];
    #pragma unroll
    for (int a = 0; a < 2; ++a)
        #pragma unroll
        for (int c = 0; c < 4; ++c) { f32x4 z = {0.f, 0.f, 0.f, 0.f}; acc[a][c] = z; }

    // ---- helpers (all loops fully unrolled; constant indices) ----
    #define ISSUE(va, vb, k0) do { \
        _Pragma("unroll") \
        for (int r = 0; r < 8; ++r) GLOAD16(va[r], xrow + (size_t)r * xstep + (k0)); \
        _Pragma("unroll") \
        for (int r = 0; r < 4; ++r) GLOAD16(vb[r], wrow + (size_t)r * wstep + (k0)); \
    } while (0)

    #define CONVERT(va, vb) do { \
        _Pragma("unroll") \
        for (int r = 0; r < 8; ++r) { \
            ushort4v h; \
            h[0] = f2bf(va[r][0]); h[1] = f2bf(va[r][1]); \
            h[2] = f2bf(va[r][2]); h[3] = f2bf(va[r][3]); \
            *(ushort4v*)&As[r * 16 + sgrp][klane] = h; \
        } \
        _Pragma("unroll") \
        for (int r = 0; r < 4; ++r) { \
            ushort4v h; \
            h[0] = f2bf(vb[r][0]); h[1] = f2bf(vb[r][1]); \
            h[2] = f2bf(vb[r][2]); h[3] = f2bf(vb[r][3]); \
            *(ushort4v*)&Bs[r * 16 + sgrp][klane] = h; \
        } \
    } while (0)

    #define MFMA_TILE() do { \
        _Pragma("unroll") \
        for (int ks = 0; ks < 2; ++ks) { \
            const int kb = ks * 32 + ((lane >> 4) << 3); \
            short8 a0 = *(const short8*)&As[w * 32 +      l15][kb]; \
            short8 a1 = *(const short8*)&As[w * 32 + 16 + l15][kb]; \
            _Pragma("unroll") \
            for (int ct = 0; ct < 4; ++ct) { \
                short8 bb = *(const short8*)&Bs[ct * 16 + l15][kb]; \
                acc[0][ct] = __builtin_amdgcn_mfma_f32_16x16x32_bf16(a0, bb, acc[0][ct], 0, 0, 0); \
                acc[1][ct] = __builtin_amdgcn_mfma_f32_16x16x32_bf16(a1, bb, acc[1][ct], 0, 0, 0); \
            } \
        } \
    } while (0)

    // ---- pipeline: 4 k-tiles, pa/qa alternating ----
    ISSUE(pa, pb, 0);

    // tile 0
    VMWAIT0();
    CONVERT(pa, pb);
    ISSUE(qa, qb, 64);          // in flight across tile0 MFMA
    LGKM0_BARRIER();
    MFMA_TILE();
    BARRIER();

    // tile 1
    VMWAIT0();
    CONVERT(qa, qb);
    ISSUE(pa, pb, 128);
    LGKM0_BARRIER();
    MFMA_TILE();
    BARRIER();

    // tile 2
    VMWAIT0();
    CONVERT(pa, pb);
    ISSUE(qa, qb, 192);
    LGKM0_BARRIER();
    MFMA_TILE();
    BARRIER();

    // tile 3
    VMWAIT0();
    CONVERT(qa, qb);
    LGKM0_BARRIER();
    MFMA_TILE();

    // ---- epilogue: D map col = lane&15, row = (lane>>4)*4 + r (verified) ----
    const int d  = l15;
    const int rq = lane >> 4;
    #pragma unroll
    for (int rt = 0; rt < 2; ++rt) {
        #pragma unroll
        for (int ct = 0; ct < 4; ++ct) {
            const int m = mc * 4 + ct;
            #pragma unroll
            for (int r = 0; r < 4; ++r) {
                const int brow = w * 32 + rt * 16 + rq * 4 + r;
                const size_t idx = (((size_t)brow * M_ + m) * N_ + n) * D_ + d;
                hat[idx] = f2bf(acc[rt][ct][r]);
            }
        }
    }
    #undef ISSUE
    #undef CONVERT
    #undef MFMA_TILE
}

// -----------------------------------------------------------------------------
// Kernel 2: dynamic routing (3 iterations), one block per batch element b.
// (unchanged — known-correct)
// -----------------------------------------------------------------------------
__global__ __launch_bounds__(512) void routing(const unsigned short* __restrict__ hat,
                                               float* __restrict__ out) {
    __shared__ float blog[M_][N_];
    __shared__ float cmax[N_];
    __shared__ float rcsum[N_];

    const int b    = blockIdx.x;
    const int tid  = threadIdx.x;
    const int lane = tid & 63;
    const int w    = tid >> 6;

    #pragma unroll
    for (int m = 0; m < M_; ++m) blog[m][tid] = 0.f;
    __syncthreads();

    float ov[4][16];

    for (int it = 0; it < 3; ++it) {
        {
            float mx = -3.4e38f;
            #pragma unroll
            for (int m = 0; m < M_; ++m) mx = fmaxf(mx, blog[m][tid]);
            float s = 0.f;
            #pragma unroll
            for (int m = 0; m < M_; ++m) s += __expf(blog[m][tid] - mx);
            cmax[tid]  = mx;
            rcsum[tid] = 1.f / s;
        }
        __syncthreads();

        float sacc[4][16];
        #pragma unroll
        for (int q = 0; q < 4; ++q)
            #pragma unroll
            for (int dd = 0; dd < 16; ++dd) sacc[q][dd] = 0.f;

        for (int r = 0; r < 8; ++r) {
            const int nn = r * 64 + lane;
            #pragma unroll
            for (int q = 0; q < 4; ++q) {
                const int m = w * 4 + q;
                const float cm = __expf(blog[m][nn] - cmax[nn]) * rcsum[nn];
                const size_t base = (((size_t)b * M_ + m) * N_ + nn) * D_;
                short8 h0 = *(const short8*)(hat + base);
                short8 h1 = *(const short8*)(hat + base + 8);
                #pragma unroll
                for (int dd = 0; dd < 8; ++dd) {
                    sacc[q][dd]     += cm * bf2f((unsigned short)h0[dd]);
                    sacc[q][8 + dd] += cm * bf2f((unsigned short)h1[dd]);
                }
            }
        }
        #pragma unroll
        for (int off = 32; off >= 1; off >>= 1) {
            #pragma unroll
            for (int q = 0; q < 4; ++q)
                #pragma unroll
                for (int dd = 0; dd < 16; ++dd)
                    sacc[q][dd] += __shfl_xor(sacc[q][dd], off, 64);
        }
        #pragma unroll
        for (int q = 0; q < 4; ++q) {
            float s2 = 0.f;
            #pragma unroll
            for (int dd = 0; dd < 16; ++dd) s2 += sacc[q][dd] * sacc[q][dd];
            const float scale = s2 / (1.f + s2) / sqrtf(s2 + 1e-7f);
            #pragma unroll
            for (int dd = 0; dd < 16; ++dd) ov[q][dd] = scale * sacc[q][dd];
        }

        if (it < 2) {
            for (int r = 0; r < 8; ++r) {
                const int nn = r * 64 + lane;
                #pragma unroll
                for (int q = 0; q < 4; ++q) {
                    const int m = w * 4 + q;
                    const size_t base = (((size_t)b * M_ + m) * N_ + nn) * D_;
                    short8 h0 = *(const short8*)(hat + base);
                    short8 h1 = *(const short8*)(hat + base + 8);
                    float dot = 0.f;
                    #pragma unroll
                    for (int dd = 0; dd < 8; ++dd) {
                        dot += ov[q][dd]     * bf2f((unsigned short)h0[dd]);
                        dot += ov[q][8 + dd] * bf2f((unsigned short)h1[dd]);
                    }
                    blog[m][nn] += dot;
                }
            }
        }
        __syncthreads();
    }

    if (lane == 0) {
        #pragma unroll
        for (int q = 0; q < 4; ++q) {
            const int m = w * 4 + q;
            #pragma unroll
            for (int c4 = 0; c4 < 4; ++c4) {
                float4v v;
                v[0] = ov[q][c4 * 4 + 0];
                v[1] = ov[q][c4 * 4 + 1];
                v[2] = ov[q][c4 * 4 + 2];
                v[3] = ov[q][c4 * 4 + 3];
                *(float4v*)&out[((size_t)b * M_ + m) * D_ + c4 * 4] = v;
            }
        }
    }
}

extern "C" void kernel_launch(void* const* d_in, const int* in_sizes, int n_in,
                              void* d_out, int out_size, void* d_ws, size_t ws_size,
                              hipStream_t stream) {
    const float* x = (const float*)d_in[0];        // [128, 512, 256] fp32
    const float* W = (const float*)d_in[1];        // [32, 512, 16, 256] fp32
    unsigned short* hat = (unsigned short*)d_ws;   // bf16 [128,32,512,16] = 64 MB
    float* out = (float*)d_out;                    // fp32 [128,32,16]

    hat_gemm<<<dim3(4096), dim3(256), 0, stream>>>(x, W, hat);
    routing<<<dim3(B_), dim3(512), 0, stream>>>(hat, out);
}